// Round 1
// baseline (530.016 us; speedup 1.0000x reference)
//
#include <hip/hip_runtime.h>
#include <math.h>

#define D_H 128
#define TM 128
#define KT 32

// ---------------- graph build ----------------

__global__ void k_zero_int(int* p, int n) {
  int i = blockIdx.x * blockDim.x + threadIdx.x;
  if (i < n) p[i] = 0;
}

__global__ void k_deg(const int* __restrict__ dstv, int* __restrict__ deg, int E) {
  for (int i = blockIdx.x * blockDim.x + threadIdx.x; i < E; i += gridDim.x * blockDim.x)
    atomicAdd(&deg[dstv[i]], 1);
}

__global__ __launch_bounds__(1024) void k_scan(const int* __restrict__ deg,
                                               int* __restrict__ row_ptr,
                                               int* __restrict__ cnt, int N) {
  __shared__ int sums[1024];
  int t = threadIdx.x;
  int chunk = (N + 1023) >> 10;
  int s0 = t * chunk;
  int s1 = min(s0 + chunk, N);
  int local = 0;
  for (int i = s0; i < s1; ++i) local += deg[i];
  sums[t] = local;
  __syncthreads();
  for (int off = 1; off < 1024; off <<= 1) {
    int v = sums[t];
    int u = (t >= off) ? sums[t - off] : 0;
    __syncthreads();
    sums[t] = v + u;
    __syncthreads();
  }
  int base = (t == 0) ? 0 : sums[t - 1];
  for (int i = s0; i < s1; ++i) {
    row_ptr[i] = base;
    cnt[i] = base;
    base += deg[i];
  }
  if (t == 1023) row_ptr[N] = base;
}

__global__ void k_scatter(const int* __restrict__ srcv, const int* __restrict__ dstv,
                          int* __restrict__ cnt, int* __restrict__ col, int E) {
  for (int i = blockIdx.x * blockDim.x + threadIdx.x; i < E; i += gridDim.x * blockDim.x) {
    int d = dstv[i];
    int pos = atomicAdd(&cnt[d], 1);
    col[pos] = srcv[i];
  }
}

// ---------------- mean aggregation (one wave per node) ----------------

__global__ __launch_bounds__(256) void k_aggregate(const float* __restrict__ h,
                                                   const int* __restrict__ row_ptr,
                                                   const int* __restrict__ col,
                                                   float* __restrict__ out, int N) {
  int wid = blockIdx.x * 4 + (threadIdx.x >> 6);
  if (wid >= N) return;
  int lane = threadIdx.x & 63;
  const float2* hv = (const float2*)h;
  int e0 = row_ptr[wid], e1 = row_ptr[wid + 1];
  float ax = 0.f, ay = 0.f;
  int e = e0;
  for (; e + 4 <= e1; e += 4) {
    int s0 = col[e], s1 = col[e + 1], s2 = col[e + 2], s3 = col[e + 3];
    float2 v0 = hv[(size_t)s0 * 64 + lane];
    float2 v1 = hv[(size_t)s1 * 64 + lane];
    float2 v2 = hv[(size_t)s2 * 64 + lane];
    float2 v3 = hv[(size_t)s3 * 64 + lane];
    ax += v0.x + v1.x + v2.x + v3.x;
    ay += v0.y + v1.y + v2.y + v3.y;
  }
  for (; e < e1; ++e) {
    float2 v = hv[(size_t)col[e] * 64 + lane];
    ax += v.x;
    ay += v.y;
  }
  float inv = 1.f / fmaxf((float)(e1 - e0), 1.f);
  float2 o;
  o.x = ax * inv;
  o.y = ay * inv;
  ((float2*)out)[(size_t)wid * 64 + lane] = o;
}

// ---------------- fused GEMM: out = [relu]( A1@W1^T (+ A2@W2^T) + bias ) ----------------
// W is [128][K] row-major. Block tile: 128 rows x 128 cols, 256 threads,
// thread = 8 rows x 8 cols (two float4 col groups).

template <bool DUAL, bool RELU>
__global__ __launch_bounds__(256) void k_gemm(const float* __restrict__ A1,
                                              const float* __restrict__ W1, int K1,
                                              const float* __restrict__ A2,
                                              const float* __restrict__ W2, int K2,
                                              const float* __restrict__ bias,
                                              float* __restrict__ out, int M) {
  __shared__ float Wt[KT][D_H];  // Wt[k][o]
  __shared__ float Xs[KT][TM];   // Xs[k][r]
  int t = threadIdx.x;
  int g = t >> 4;   // 0..15 -> rows 8g..8g+7
  int c = t & 15;   // cols 4c..4c+3 and 64+4c..64+4c+3
  int row0 = blockIdx.x * TM;

  float acc[8][8];
#pragma unroll
  for (int i = 0; i < 8; ++i)
#pragma unroll
    for (int j = 0; j < 8; ++j) acc[i][j] = 0.f;

  int npass = DUAL ? 2 : 1;
  for (int pass = 0; pass < npass; ++pass) {
    const float* A = pass ? A2 : A1;
    const float* W = pass ? W2 : W1;
    int K = pass ? K2 : K1;
    for (int k0 = 0; k0 < K; k0 += KT) {
      // stage W tile (transpose to Wt[k][o])
      {
        int o = t >> 1;
        int kh = (t & 1) << 4;
        const float* Wrow = W + (size_t)o * K;
#pragma unroll
        for (int i = 0; i < 4; ++i) {
          int kl = kh + (i << 2);
          int kg = k0 + kl;
          float4 v = make_float4(0.f, 0.f, 0.f, 0.f);
          if (kg + 3 < K) v = *(const float4*)(Wrow + kg);
          Wt[kl + 0][o] = v.x;
          Wt[kl + 1][o] = v.y;
          Wt[kl + 2][o] = v.z;
          Wt[kl + 3][o] = v.w;
        }
      }
      // stage X tile (transpose to Xs[k][r])
      {
        int r = t >> 1;
        int kh = (t & 1) << 4;
        int grow = row0 + r;
        bool ok = grow < M;
        const float* Arow = A + (size_t)grow * K;
#pragma unroll
        for (int i = 0; i < 4; ++i) {
          int kl = kh + (i << 2);
          int kg = k0 + kl;
          float4 v = make_float4(0.f, 0.f, 0.f, 0.f);
          if (ok && kg + 3 < K) v = *(const float4*)(Arow + kg);
          Xs[kl + 0][r] = v.x;
          Xs[kl + 1][r] = v.y;
          Xs[kl + 2][r] = v.z;
          Xs[kl + 3][r] = v.w;
        }
      }
      __syncthreads();
#pragma unroll 8
      for (int k = 0; k < KT; ++k) {
        float4 w0 = *(const float4*)&Wt[k][c << 2];
        float4 w1 = *(const float4*)&Wt[k][64 + (c << 2)];
        float4 x0 = *(const float4*)&Xs[k][g << 3];
        float4 x1 = *(const float4*)&Xs[k][(g << 3) + 4];
        float xr[8] = {x0.x, x0.y, x0.z, x0.w, x1.x, x1.y, x1.z, x1.w};
#pragma unroll
        for (int rr = 0; rr < 8; ++rr) {
          acc[rr][0] = fmaf(xr[rr], w0.x, acc[rr][0]);
          acc[rr][1] = fmaf(xr[rr], w0.y, acc[rr][1]);
          acc[rr][2] = fmaf(xr[rr], w0.z, acc[rr][2]);
          acc[rr][3] = fmaf(xr[rr], w0.w, acc[rr][3]);
          acc[rr][4] = fmaf(xr[rr], w1.x, acc[rr][4]);
          acc[rr][5] = fmaf(xr[rr], w1.y, acc[rr][5]);
          acc[rr][6] = fmaf(xr[rr], w1.z, acc[rr][6]);
          acc[rr][7] = fmaf(xr[rr], w1.w, acc[rr][7]);
        }
      }
      __syncthreads();
    }
  }

  float4 b0 = *(const float4*)&bias[c << 2];
  float4 b1 = *(const float4*)&bias[64 + (c << 2)];
#pragma unroll
  for (int rr = 0; rr < 8; ++rr) {
    int grow = row0 + (g << 3) + rr;
    if (grow < M) {
      float4 o0, o1;
      o0.x = acc[rr][0] + b0.x;
      o0.y = acc[rr][1] + b0.y;
      o0.z = acc[rr][2] + b0.z;
      o0.w = acc[rr][3] + b0.w;
      o1.x = acc[rr][4] + b1.x;
      o1.y = acc[rr][5] + b1.y;
      o1.z = acc[rr][6] + b1.z;
      o1.w = acc[rr][7] + b1.w;
      if (RELU) {
        o0.x = fmaxf(o0.x, 0.f); o0.y = fmaxf(o0.y, 0.f);
        o0.z = fmaxf(o0.z, 0.f); o0.w = fmaxf(o0.w, 0.f);
        o1.x = fmaxf(o1.x, 0.f); o1.y = fmaxf(o1.y, 0.f);
        o1.z = fmaxf(o1.z, 0.f); o1.w = fmaxf(o1.w, 0.f);
      }
      float4* orow = (float4*)(out + (size_t)grow * D_H);
      orow[c] = o0;
      orow[16 + c] = o1;
    }
  }
}

// ---------------- attention readout ----------------

__global__ __launch_bounds__(256) void k_score(const float* __restrict__ h,
                                               const float* __restrict__ watt,
                                               const float* __restrict__ batt,
                                               float* __restrict__ scores,
                                               float* __restrict__ partmax, int N) {
  __shared__ float smax[16];
  int t = threadIdx.x;
  int grp = t >> 4, l = t & 15;
  int node = blockIdx.x * 16 + grp;
  float sc = -3.0e38f;
  if (node < N) {
    const float2* hv = (const float2*)(h + (size_t)node * D_H);
    const float2* wv = (const float2*)watt;
    float acc = 0.f;
#pragma unroll
    for (int i = 0; i < 4; ++i) {
      float2 a = hv[i * 16 + l];
      float2 w = wv[i * 16 + l];
      acc = fmaf(a.x, w.x, acc);
      acc = fmaf(a.y, w.y, acc);
    }
#pragma unroll
    for (int off = 8; off > 0; off >>= 1) acc += __shfl_down(acc, off, 16);
    if (l == 0) {
      sc = acc + batt[0];
      scores[node] = sc;
    }
  }
  if (l == 0) smax[grp] = sc;
  __syncthreads();
  if (t == 0) {
    float m = smax[0];
    for (int i = 1; i < 16; ++i) m = fmaxf(m, smax[i]);
    partmax[blockIdx.x] = m;
  }
}

// red[0]=M, red[1]=Z, red[2..1025]=pooled_u[8][128]
__global__ __launch_bounds__(256) void k_redmax(const float* __restrict__ partmax, int PB,
                                                float* __restrict__ red) {
  __shared__ float sm[256];
  int t = threadIdx.x;
  float m = -3.0e38f;
  for (int i = t; i < PB; i += 256) m = fmaxf(m, partmax[i]);
  sm[t] = m;
  __syncthreads();
  for (int off = 128; off > 0; off >>= 1) {
    if (t < off) sm[t] = fmaxf(sm[t], sm[t + off]);
    __syncthreads();
  }
  if (t == 0) {
    red[0] = sm[0];
    red[1] = 0.f;
  }
  for (int i = t; i < 1024; i += 256) red[2 + i] = 0.f;
}

__global__ __launch_bounds__(256) void k_pool(const float* __restrict__ h,
                                              const float* __restrict__ scores,
                                              const int* __restrict__ batch,
                                              float* __restrict__ red, int N, int nblocks) {
  __shared__ float pl[4][1024];
  __shared__ float zp[4];
  int t = threadIdx.x;
  int w = t >> 6, lane = t & 63;
  for (int i = lane; i < 1024; i += 64) pl[w][i] = 0.f;
  float M = red[0];
  float zacc = 0.f;
  const float2* hv = (const float2*)h;
  int stride = nblocks * 4;
  for (int node = blockIdx.x * 4 + w; node < N; node += stride) {
    float wgt = __expf(scores[node] - M);
    int b = batch[node];
    float2 v = hv[(size_t)node * 64 + lane];
    pl[w][b * 128 + lane * 2] += v.x * wgt;
    pl[w][b * 128 + lane * 2 + 1] += v.y * wgt;
    zacc += wgt;
  }
  if (lane == 0) zp[w] = zacc;
  __syncthreads();
  for (int i = t; i < 1024; i += 256) {
    float s = pl[0][i] + pl[1][i] + pl[2][i] + pl[3][i];
    atomicAdd(&red[2 + i], s);
  }
  if (t == 0) atomicAdd(&red[1], zp[0] + zp[1] + zp[2] + zp[3]);
}

__global__ __launch_bounds__(512) void k_out(const float* __restrict__ red,
                                             const float* __restrict__ Wout,
                                             const float* __restrict__ bout,
                                             float* __restrict__ out) {
  int t = threadIdx.x;
  int gIdx = t >> 6, o = t & 63;
  float invZ = 1.f / red[1];
  const float* p = red + 2 + gIdx * 128;
  const float* wr = Wout + (size_t)o * 128;
  float acc = 0.f;
  for (int k = 0; k < 128; ++k) acc = fmaf(p[k], wr[k], acc);
  out[gIdx * 64 + o] = acc * invZ + bout[o];
}

// ---------------- launcher ----------------

extern "C" void kernel_launch(void* const* d_in, const int* in_sizes, int n_in,
                              void* d_out, int out_size, void* d_ws, size_t ws_size,
                              hipStream_t stream) {
  const float* x     = (const float*)d_in[0];
  const int*   ei    = (const int*)d_in[1];
  const int*   batch = (const int*)d_in[2];
  const float* W_emb = (const float*)d_in[3];
  const float* b_emb = (const float*)d_in[4];
  const float* Wl0   = (const float*)d_in[5];
  const float* bl0   = (const float*)d_in[6];
  const float* Wr0   = (const float*)d_in[7];
  const float* Wl1   = (const float*)d_in[8];
  const float* bl1   = (const float*)d_in[9];
  const float* Wr1   = (const float*)d_in[10];
  const float* W_att = (const float*)d_in[11];
  const float* b_att = (const float*)d_in[12];
  const float* W_out = (const float*)d_in[13];
  const float* b_out = (const float*)d_in[14];
  float* out = (float*)d_out;

  const int DIN = 300;
  int N = in_sizes[0] / DIN;
  int E = in_sizes[1] / 2;

  char* wsp = (char*)d_ws;
  size_t off = 0;
  auto carve = [&](size_t bytes) -> void* {
    void* p = wsp + off;
    off += (bytes + 255) & ~(size_t)255;
    return p;
  };
  float* A       = (float*)carve((size_t)N * D_H * 4);
  float* B       = (float*)carve((size_t)N * D_H * 4);
  int*   colA    = (int*)carve((size_t)E * 4);
  int*   row_ptr = (int*)carve((size_t)(N + 1) * 4);
  int*   deg     = (int*)carve((size_t)N * 4);
  int*   cnt     = (int*)carve((size_t)N * 4);
  float* scores  = (float*)carve((size_t)N * 4);
  int scoreBlocks = (N + 15) / 16;
  float* partmax = (float*)carve((size_t)scoreBlocks * 4);
  float* red     = (float*)carve((size_t)(2 + 1024) * 4);

  const int* srcv = ei;
  const int* dstv = ei + E;

  k_zero_int<<<(N + 255) / 256, 256, 0, stream>>>(deg, N);
  k_deg<<<1024, 256, 0, stream>>>(dstv, deg, E);
  k_scan<<<1, 1024, 0, stream>>>(deg, row_ptr, cnt, N);
  k_scatter<<<1024, 256, 0, stream>>>(srcv, dstv, cnt, colA, E);

  int gblocks = (N + TM - 1) / TM;
  k_gemm<false, false><<<gblocks, 256, 0, stream>>>(x, W_emb, DIN, nullptr, nullptr, 0,
                                                    b_emb, A, N);
  k_aggregate<<<(N + 3) / 4, 256, 0, stream>>>(A, row_ptr, colA, B, N);
  k_gemm<true, true><<<gblocks, 256, 0, stream>>>(B, Wl0, D_H, A, Wr0, D_H, bl0, B, N);
  k_aggregate<<<(N + 3) / 4, 256, 0, stream>>>(B, row_ptr, colA, A, N);
  k_gemm<true, true><<<gblocks, 256, 0, stream>>>(A, Wl1, D_H, B, Wr1, D_H, bl1, A, N);

  k_score<<<scoreBlocks, 256, 0, stream>>>(A, W_att, b_att, scores, partmax, N);
  k_redmax<<<1, 256, 0, stream>>>(partmax, scoreBlocks, red);
  k_pool<<<256, 256, 0, stream>>>(A, scores, batch, red, N, 256);
  k_out<<<1, 512, 0, stream>>>(red, W_out, b_out, out);
}

// Round 2
// 429.977 us; speedup vs baseline: 1.2327x; 1.2327x over previous
//
#include <hip/hip_runtime.h>
#include <math.h>

#define D_H 128
#define TM 128
#define KT 32

// ---------------- graph build ----------------

__global__ void k_deg(const int* __restrict__ dstv, int* __restrict__ deg, int E) {
  for (int i = blockIdx.x * blockDim.x + threadIdx.x; i < E; i += gridDim.x * blockDim.x)
    atomicAdd(&deg[dstv[i]], 1);
}

// stage 1: per-block (256-elem chunk) sum of deg
__global__ __launch_bounds__(256) void k_partial(const int* __restrict__ deg,
                                                 int* __restrict__ partials, int N) {
  __shared__ int s[256];
  int t = threadIdx.x;
  int i = blockIdx.x * 256 + t;
  s[t] = (i < N) ? deg[i] : 0;
  __syncthreads();
  for (int off = 128; off > 0; off >>= 1) {
    if (t < off) s[t] += s[t + off];
    __syncthreads();
  }
  if (t == 0) partials[blockIdx.x] = s[0];
}

// stage 2: single-block exclusive scan of block partials (NB <= 256)
__global__ __launch_bounds__(256) void k_scanpart(int* __restrict__ partials, int NB,
                                                  int* __restrict__ row_ptr, int N) {
  __shared__ int s[256];
  int t = threadIdx.x;
  int v = (t < NB) ? partials[t] : 0;
  s[t] = v;
  __syncthreads();
  for (int off = 1; off < 256; off <<= 1) {
    int u = (t >= off) ? s[t - off] : 0;
    __syncthreads();
    s[t] += u;
    __syncthreads();
  }
  if (t < NB) partials[t] = s[t] - v;  // exclusive prefix
  if (t == 255) row_ptr[N] = s[255];   // total
}

// stage 3: per-block exclusive scan + block offset -> row_ptr, cnt
__global__ __launch_bounds__(256) void k_rowptr(const int* __restrict__ deg,
                                                const int* __restrict__ partials,
                                                int* __restrict__ row_ptr,
                                                int* __restrict__ cnt, int N) {
  __shared__ int s[256];
  int t = threadIdx.x;
  int i = blockIdx.x * 256 + t;
  int v = (i < N) ? deg[i] : 0;
  s[t] = v;
  __syncthreads();
  for (int off = 1; off < 256; off <<= 1) {
    int u = (t >= off) ? s[t - off] : 0;
    __syncthreads();
    s[t] += u;
    __syncthreads();
  }
  if (i < N) {
    int ex = partials[blockIdx.x] + s[t] - v;
    row_ptr[i] = ex;
    cnt[i] = ex;
  }
}

__global__ void k_scatter(const int* __restrict__ srcv, const int* __restrict__ dstv,
                          int* __restrict__ cnt, int* __restrict__ col, int E) {
  for (int i = blockIdx.x * blockDim.x + threadIdx.x; i < E; i += gridDim.x * blockDim.x) {
    int d = dstv[i];
    int pos = atomicAdd(&cnt[d], 1);
    col[pos] = srcv[i];
  }
}

// ---------------- mean aggregation (one wave per node) ----------------

__global__ __launch_bounds__(256) void k_aggregate(const float* __restrict__ h,
                                                   const int* __restrict__ row_ptr,
                                                   const int* __restrict__ col,
                                                   float* __restrict__ out, int N) {
  int wid = blockIdx.x * 4 + (threadIdx.x >> 6);
  if (wid >= N) return;
  int lane = threadIdx.x & 63;
  const float2* hv = (const float2*)h;
  int e0 = row_ptr[wid], e1 = row_ptr[wid + 1];
  float ax = 0.f, ay = 0.f;
  int e = e0;
  for (; e + 4 <= e1; e += 4) {
    int s0 = col[e], s1 = col[e + 1], s2 = col[e + 2], s3 = col[e + 3];
    float2 v0 = hv[(size_t)s0 * 64 + lane];
    float2 v1 = hv[(size_t)s1 * 64 + lane];
    float2 v2 = hv[(size_t)s2 * 64 + lane];
    float2 v3 = hv[(size_t)s3 * 64 + lane];
    ax += v0.x + v1.x + v2.x + v3.x;
    ay += v0.y + v1.y + v2.y + v3.y;
  }
  for (; e < e1; ++e) {
    float2 v = hv[(size_t)col[e] * 64 + lane];
    ax += v.x;
    ay += v.y;
  }
  float inv = 1.f / fmaxf((float)(e1 - e0), 1.f);
  float2 o;
  o.x = ax * inv;
  o.y = ay * inv;
  ((float2*)out)[(size_t)wid * 64 + lane] = o;
}

// ---------------- fused GEMM: out = [relu]( A1@W1^T (+ A2@W2^T) + bias ) ----------------

template <bool DUAL, bool RELU>
__global__ __launch_bounds__(256) void k_gemm(const float* __restrict__ A1,
                                              const float* __restrict__ W1, int K1,
                                              const float* __restrict__ A2,
                                              const float* __restrict__ W2, int K2,
                                              const float* __restrict__ bias,
                                              float* __restrict__ out, int M) {
  __shared__ float Wt[KT][D_H];  // Wt[k][o]
  __shared__ float Xs[KT][TM];   // Xs[k][r]
  int t = threadIdx.x;
  int g = t >> 4;   // 0..15 -> rows 8g..8g+7
  int c = t & 15;   // cols 4c..4c+3 and 64+4c..64+4c+3
  int row0 = blockIdx.x * TM;

  float acc[8][8];
#pragma unroll
  for (int i = 0; i < 8; ++i)
#pragma unroll
    for (int j = 0; j < 8; ++j) acc[i][j] = 0.f;

  int npass = DUAL ? 2 : 1;
  for (int pass = 0; pass < npass; ++pass) {
    const float* A = pass ? A2 : A1;
    const float* W = pass ? W2 : W1;
    int K = pass ? K2 : K1;
    for (int k0 = 0; k0 < K; k0 += KT) {
      {
        int o = t >> 1;
        int kh = (t & 1) << 4;
        const float* Wrow = W + (size_t)o * K;
#pragma unroll
        for (int i = 0; i < 4; ++i) {
          int kl = kh + (i << 2);
          int kg = k0 + kl;
          float4 v = make_float4(0.f, 0.f, 0.f, 0.f);
          if (kg + 3 < K) v = *(const float4*)(Wrow + kg);
          Wt[kl + 0][o] = v.x;
          Wt[kl + 1][o] = v.y;
          Wt[kl + 2][o] = v.z;
          Wt[kl + 3][o] = v.w;
        }
      }
      {
        int r = t >> 1;
        int kh = (t & 1) << 4;
        int grow = row0 + r;
        bool ok = grow < M;
        const float* Arow = A + (size_t)grow * K;
#pragma unroll
        for (int i = 0; i < 4; ++i) {
          int kl = kh + (i << 2);
          int kg = k0 + kl;
          float4 v = make_float4(0.f, 0.f, 0.f, 0.f);
          if (ok && kg + 3 < K) v = *(const float4*)(Arow + kg);
          Xs[kl + 0][r] = v.x;
          Xs[kl + 1][r] = v.y;
          Xs[kl + 2][r] = v.z;
          Xs[kl + 3][r] = v.w;
        }
      }
      __syncthreads();
#pragma unroll 8
      for (int k = 0; k < KT; ++k) {
        float4 w0 = *(const float4*)&Wt[k][c << 2];
        float4 w1 = *(const float4*)&Wt[k][64 + (c << 2)];
        float4 x0 = *(const float4*)&Xs[k][g << 3];
        float4 x1 = *(const float4*)&Xs[k][(g << 3) + 4];
        float xr[8] = {x0.x, x0.y, x0.z, x0.w, x1.x, x1.y, x1.z, x1.w};
#pragma unroll
        for (int rr = 0; rr < 8; ++rr) {
          acc[rr][0] = fmaf(xr[rr], w0.x, acc[rr][0]);
          acc[rr][1] = fmaf(xr[rr], w0.y, acc[rr][1]);
          acc[rr][2] = fmaf(xr[rr], w0.z, acc[rr][2]);
          acc[rr][3] = fmaf(xr[rr], w0.w, acc[rr][3]);
          acc[rr][4] = fmaf(xr[rr], w1.x, acc[rr][4]);
          acc[rr][5] = fmaf(xr[rr], w1.y, acc[rr][5]);
          acc[rr][6] = fmaf(xr[rr], w1.z, acc[rr][6]);
          acc[rr][7] = fmaf(xr[rr], w1.w, acc[rr][7]);
        }
      }
      __syncthreads();
    }
  }

  float4 b0 = *(const float4*)&bias[c << 2];
  float4 b1 = *(const float4*)&bias[64 + (c << 2)];
#pragma unroll
  for (int rr = 0; rr < 8; ++rr) {
    int grow = row0 + (g << 3) + rr;
    if (grow < M) {
      float4 o0, o1;
      o0.x = acc[rr][0] + b0.x;
      o0.y = acc[rr][1] + b0.y;
      o0.z = acc[rr][2] + b0.z;
      o0.w = acc[rr][3] + b0.w;
      o1.x = acc[rr][4] + b1.x;
      o1.y = acc[rr][5] + b1.y;
      o1.z = acc[rr][6] + b1.z;
      o1.w = acc[rr][7] + b1.w;
      if (RELU) {
        o0.x = fmaxf(o0.x, 0.f); o0.y = fmaxf(o0.y, 0.f);
        o0.z = fmaxf(o0.z, 0.f); o0.w = fmaxf(o0.w, 0.f);
        o1.x = fmaxf(o1.x, 0.f); o1.y = fmaxf(o1.y, 0.f);
        o1.z = fmaxf(o1.z, 0.f); o1.w = fmaxf(o1.w, 0.f);
      }
      float4* orow = (float4*)(out + (size_t)grow * D_H);
      orow[c] = o0;
      orow[16 + c] = o1;
    }
  }
}

// ---------------- attention readout ----------------

__global__ __launch_bounds__(256) void k_score(const float* __restrict__ h,
                                               const float* __restrict__ watt,
                                               const float* __restrict__ batt,
                                               float* __restrict__ scores,
                                               float* __restrict__ partmax, int N) {
  __shared__ float smax[16];
  int t = threadIdx.x;
  int grp = t >> 4, l = t & 15;
  int node = blockIdx.x * 16 + grp;
  float sc = -3.0e38f;
  if (node < N) {
    const float2* hv = (const float2*)(h + (size_t)node * D_H);
    const float2* wv = (const float2*)watt;
    float acc = 0.f;
#pragma unroll
    for (int i = 0; i < 4; ++i) {
      float2 a = hv[i * 16 + l];
      float2 w = wv[i * 16 + l];
      acc = fmaf(a.x, w.x, acc);
      acc = fmaf(a.y, w.y, acc);
    }
#pragma unroll
    for (int off = 8; off > 0; off >>= 1) acc += __shfl_down(acc, off, 16);
    if (l == 0) {
      sc = acc + batt[0];
      scores[node] = sc;
    }
  }
  if (l == 0) smax[grp] = sc;
  __syncthreads();
  if (t == 0) {
    float m = smax[0];
    for (int i = 1; i < 16; ++i) m = fmaxf(m, smax[i]);
    partmax[blockIdx.x] = m;
  }
}

// red[0]=M, red[1]=Z, red[2..1025]=pooled_u[8][128]
__global__ __launch_bounds__(256) void k_redmax(const float* __restrict__ partmax, int PB,
                                                float* __restrict__ red) {
  __shared__ float sm[256];
  int t = threadIdx.x;
  float m = -3.0e38f;
  for (int i = t; i < PB; i += 256) m = fmaxf(m, partmax[i]);
  sm[t] = m;
  __syncthreads();
  for (int off = 128; off > 0; off >>= 1) {
    if (t < off) sm[t] = fmaxf(sm[t], sm[t + off]);
    __syncthreads();
  }
  if (t == 0) {
    red[0] = sm[0];
    red[1] = 0.f;
  }
  for (int i = t; i < 1024; i += 256) red[2 + i] = 0.f;
}

__global__ __launch_bounds__(256) void k_pool(const float* __restrict__ h,
                                              const float* __restrict__ scores,
                                              const int* __restrict__ batch,
                                              float* __restrict__ red, int N, int nblocks) {
  __shared__ float pl[4][1024];
  __shared__ float zp[4];
  int t = threadIdx.x;
  int w = t >> 6, lane = t & 63;
  for (int i = lane; i < 1024; i += 64) pl[w][i] = 0.f;
  float M = red[0];
  float zacc = 0.f;
  const float2* hv = (const float2*)h;
  int stride = nblocks * 4;
  for (int node = blockIdx.x * 4 + w; node < N; node += stride) {
    float wgt = __expf(scores[node] - M);
    int b = batch[node];
    float2 v = hv[(size_t)node * 64 + lane];
    pl[w][b * 128 + lane * 2] += v.x * wgt;
    pl[w][b * 128 + lane * 2 + 1] += v.y * wgt;
    zacc += wgt;
  }
  if (lane == 0) zp[w] = zacc;
  __syncthreads();
  for (int i = t; i < 1024; i += 256) {
    float s = pl[0][i] + pl[1][i] + pl[2][i] + pl[3][i];
    atomicAdd(&red[2 + i], s);
  }
  if (t == 0) atomicAdd(&red[1], zp[0] + zp[1] + zp[2] + zp[3]);
}

__global__ __launch_bounds__(512) void k_out(const float* __restrict__ red,
                                             const float* __restrict__ Wout,
                                             const float* __restrict__ bout,
                                             float* __restrict__ out) {
  int t = threadIdx.x;
  int gIdx = t >> 6, o = t & 63;
  float invZ = 1.f / red[1];
  const float* p = red + 2 + gIdx * 128;
  const float* wr = Wout + (size_t)o * 128;
  float acc = 0.f;
  for (int k = 0; k < 128; ++k) acc = fmaf(p[k], wr[k], acc);
  out[gIdx * 64 + o] = acc * invZ + bout[o];
}

// ---------------- launcher ----------------

extern "C" void kernel_launch(void* const* d_in, const int* in_sizes, int n_in,
                              void* d_out, int out_size, void* d_ws, size_t ws_size,
                              hipStream_t stream) {
  const float* x     = (const float*)d_in[0];
  const int*   ei    = (const int*)d_in[1];
  const int*   batch = (const int*)d_in[2];
  const float* W_emb = (const float*)d_in[3];
  const float* b_emb = (const float*)d_in[4];
  const float* Wl0   = (const float*)d_in[5];
  const float* bl0   = (const float*)d_in[6];
  const float* Wr0   = (const float*)d_in[7];
  const float* Wl1   = (const float*)d_in[8];
  const float* bl1   = (const float*)d_in[9];
  const float* Wr1   = (const float*)d_in[10];
  const float* W_att = (const float*)d_in[11];
  const float* b_att = (const float*)d_in[12];
  const float* W_out = (const float*)d_in[13];
  const float* b_out = (const float*)d_in[14];
  float* out = (float*)d_out;

  const int DIN = 300;
  int N = in_sizes[0] / DIN;
  int E = in_sizes[1] / 2;

  char* wsp = (char*)d_ws;
  size_t off = 0;
  auto carve = [&](size_t bytes) -> void* {
    void* p = wsp + off;
    off += (bytes + 255) & ~(size_t)255;
    return p;
  };
  float* A       = (float*)carve((size_t)N * D_H * 4);
  float* B       = (float*)carve((size_t)N * D_H * 4);
  int*   colA    = (int*)carve((size_t)E * 4);
  int*   row_ptr = (int*)carve((size_t)(N + 1) * 4);
  int*   deg     = (int*)carve((size_t)N * 4);
  int*   cnt     = (int*)carve((size_t)N * 4);
  float* scores  = (float*)carve((size_t)N * 4);
  int scoreBlocks = (N + 15) / 16;
  float* partmax = (float*)carve((size_t)scoreBlocks * 4);
  float* red     = (float*)carve((size_t)(2 + 1024) * 4);
  int scanBlocks = (N + 255) / 256;
  int*   partials = (int*)carve((size_t)scanBlocks * 4);

  const int* srcv = ei;
  const int* dstv = ei + E;

  hipMemsetAsync(deg, 0, (size_t)N * 4, stream);
  k_deg<<<1024, 256, 0, stream>>>(dstv, deg, E);
  k_partial<<<scanBlocks, 256, 0, stream>>>(deg, partials, N);
  k_scanpart<<<1, 256, 0, stream>>>(partials, scanBlocks, row_ptr, N);
  k_rowptr<<<scanBlocks, 256, 0, stream>>>(deg, partials, row_ptr, cnt, N);
  k_scatter<<<1024, 256, 0, stream>>>(srcv, dstv, cnt, colA, E);

  int gblocks = (N + TM - 1) / TM;
  k_gemm<false, false><<<gblocks, 256, 0, stream>>>(x, W_emb, DIN, nullptr, nullptr, 0,
                                                    b_emb, A, N);
  k_aggregate<<<(N + 3) / 4, 256, 0, stream>>>(A, row_ptr, colA, B, N);
  k_gemm<true, true><<<gblocks, 256, 0, stream>>>(B, Wl0, D_H, A, Wr0, D_H, bl0, B, N);
  k_aggregate<<<(N + 3) / 4, 256, 0, stream>>>(B, row_ptr, colA, A, N);
  k_gemm<true, true><<<gblocks, 256, 0, stream>>>(A, Wl1, D_H, B, Wr1, D_H, bl1, A, N);

  k_score<<<scoreBlocks, 256, 0, stream>>>(A, W_att, b_att, scores, partmax, N);
  k_redmax<<<1, 256, 0, stream>>>(partmax, scoreBlocks, red);
  k_pool<<<256, 256, 0, stream>>>(A, scores, batch, red, N, 256);
  k_out<<<1, 512, 0, stream>>>(red, W_out, b_out, out);
}

// Round 3
// 377.761 us; speedup vs baseline: 1.4030x; 1.1382x over previous
//
#include <hip/hip_runtime.h>
#include <math.h>

#define D_H 128

typedef __attribute__((ext_vector_type(8))) __bf16 bf16x8;
typedef __attribute__((ext_vector_type(4))) float f32x4;

// ---------------- graph build ----------------

__global__ void k_deg(const int* __restrict__ dstv, int* __restrict__ deg, int E) {
  for (int i = blockIdx.x * blockDim.x + threadIdx.x; i < E; i += gridDim.x * blockDim.x)
    atomicAdd(&deg[dstv[i]], 1);
}

__global__ __launch_bounds__(256) void k_partial(const int* __restrict__ deg,
                                                 int* __restrict__ partials, int N) {
  __shared__ int s[256];
  int t = threadIdx.x;
  int i = blockIdx.x * 256 + t;
  s[t] = (i < N) ? deg[i] : 0;
  __syncthreads();
  for (int off = 128; off > 0; off >>= 1) {
    if (t < off) s[t] += s[t + off];
    __syncthreads();
  }
  if (t == 0) partials[blockIdx.x] = s[0];
}

__global__ __launch_bounds__(256) void k_scanpart(int* __restrict__ partials, int NB,
                                                  int* __restrict__ row_ptr, int N) {
  __shared__ int s[256];
  int t = threadIdx.x;
  int v = (t < NB) ? partials[t] : 0;
  s[t] = v;
  __syncthreads();
  for (int off = 1; off < 256; off <<= 1) {
    int u = (t >= off) ? s[t - off] : 0;
    __syncthreads();
    s[t] += u;
    __syncthreads();
  }
  if (t < NB) partials[t] = s[t] - v;
  if (t == 255) row_ptr[N] = s[255];
}

__global__ __launch_bounds__(256) void k_rowptr(const int* __restrict__ deg,
                                                const int* __restrict__ partials,
                                                int* __restrict__ row_ptr,
                                                int* __restrict__ cnt, int N) {
  __shared__ int s[256];
  int t = threadIdx.x;
  int i = blockIdx.x * 256 + t;
  int v = (i < N) ? deg[i] : 0;
  s[t] = v;
  __syncthreads();
  for (int off = 1; off < 256; off <<= 1) {
    int u = (t >= off) ? s[t - off] : 0;
    __syncthreads();
    s[t] += u;
    __syncthreads();
  }
  if (i < N) {
    int ex = partials[blockIdx.x] + s[t] - v;
    row_ptr[i] = ex;
    cnt[i] = ex;
  }
}

__global__ void k_scatter(const int* __restrict__ srcv, const int* __restrict__ dstv,
                          int* __restrict__ cnt, int* __restrict__ col, int E) {
  for (int i = blockIdx.x * blockDim.x + threadIdx.x; i < E; i += gridDim.x * blockDim.x) {
    int d = dstv[i];
    int pos = atomicAdd(&cnt[d], 1);
    col[pos] = srcv[i];
  }
}

// ---------------- mean aggregation (one wave per node) ----------------

__global__ __launch_bounds__(256) void k_aggregate(const float* __restrict__ h,
                                                   const int* __restrict__ row_ptr,
                                                   const int* __restrict__ col,
                                                   float* __restrict__ out, int N) {
  int wid = blockIdx.x * 4 + (threadIdx.x >> 6);
  if (wid >= N) return;
  int lane = threadIdx.x & 63;
  const float2* hv = (const float2*)h;
  int e0 = row_ptr[wid], e1 = row_ptr[wid + 1];
  float ax = 0.f, ay = 0.f;
  int e = e0;
  for (; e + 4 <= e1; e += 4) {
    int s0 = col[e], s1 = col[e + 1], s2 = col[e + 2], s3 = col[e + 3];
    float2 v0 = hv[(size_t)s0 * 64 + lane];
    float2 v1 = hv[(size_t)s1 * 64 + lane];
    float2 v2 = hv[(size_t)s2 * 64 + lane];
    float2 v3 = hv[(size_t)s3 * 64 + lane];
    ax += v0.x + v1.x + v2.x + v3.x;
    ay += v0.y + v1.y + v2.y + v3.y;
  }
  for (; e < e1; ++e) {
    float2 v = hv[(size_t)col[e] * 64 + lane];
    ax += v.x;
    ay += v.y;
  }
  float inv = 1.f / fmaxf((float)(e1 - e0), 1.f);
  float2 o;
  o.x = ax * inv;
  o.y = ay * inv;
  ((float2*)out)[(size_t)wid * 64 + lane] = o;
}

// ---------------- split-bf16 MFMA GEMM ----------------
// out = [relu]( A1@W1^T (+ A2@W2^T) + bias ), A [M][K] fp32, W [128][K] fp32.
// A*W ~= Ah*Wh + Ah*Wl + Al*Wh  (each operand truncated to bf16 + bf16 residual)
// Block: 128 rows x 128 cols, 256 thr = 4 waves (2x2 of 64x64 wave tiles).
// LDS [128][64] bf16 per operand-half, XOR-swizzled: idx = r*64 + (k ^ ((r&7)<<3)).

__device__ __forceinline__ void split_bf16(float v, unsigned short& hi, unsigned short& lo) {
  unsigned int u = __float_as_uint(v);
  hi = (unsigned short)(u >> 16);
  float l = v - __uint_as_float(u & 0xffff0000u);
  lo = (unsigned short)(__float_as_uint(l) >> 16);
}

template <bool DUAL, bool RELU>
__global__ __launch_bounds__(256) void k_gemm(const float* __restrict__ A1,
                                              const float* __restrict__ W1, int K1,
                                              const float* __restrict__ A2,
                                              const float* __restrict__ W2, int K2,
                                              const float* __restrict__ bias,
                                              float* __restrict__ out, int M) {
  __shared__ unsigned short sAh[128 * 64];
  __shared__ unsigned short sAl[128 * 64];
  __shared__ unsigned short sWh[128 * 64];
  __shared__ unsigned short sWl[128 * 64];

  int t = threadIdx.x;
  int lane = t & 63;
  int wave = t >> 6;
  int wr = wave >> 1, wc = wave & 1;
  int row0 = blockIdx.x * 128;

  f32x4 acc[4][4] = {};

  // staging: thread t handles row (t>>1), k-half (t&1)*32
  int sr = t >> 1;
  int sk = (t & 1) * 32;
  int srx = (sr & 7) << 3;

  // fragment indices
  int fr = lane & 15;
  int fk = (lane >> 4) * 8;

  int npass = DUAL ? 2 : 1;
  for (int pass = 0; pass < npass; ++pass) {
    const float* A = pass ? A2 : A1;
    const float* W = pass ? W2 : W1;
    int K = pass ? K2 : K1;
    for (int k0 = 0; k0 < K; k0 += 64) {
      // ---- stage A tile [128][64] ----
      {
        int grow = row0 + sr;
        bool rok = grow < M;
        const float* Arow = A + (size_t)grow * K + k0 + sk;
#pragma unroll
        for (int i = 0; i < 8; ++i) {
          int kg = k0 + sk + i * 4;
          float4 v = make_float4(0.f, 0.f, 0.f, 0.f);
          if (rok && kg < K) v = *(const float4*)(Arow + i * 4);
          unsigned short hx, lx, hy, ly, hz, lz, hw, lw;
          split_bf16(v.x, hx, lx);
          split_bf16(v.y, hy, ly);
          split_bf16(v.z, hz, lz);
          split_bf16(v.w, hw, lw);
          int idx = sr * 64 + ((sk + i * 4) ^ srx);
          *(ushort4*)&sAh[idx] = make_ushort4(hx, hy, hz, hw);
          *(ushort4*)&sAl[idx] = make_ushort4(lx, ly, lz, lw);
        }
      }
      // ---- stage W tile [128][64] ----
      {
        const float* Wrow = W + (size_t)sr * K + k0 + sk;
#pragma unroll
        for (int i = 0; i < 8; ++i) {
          int kg = k0 + sk + i * 4;
          float4 v = make_float4(0.f, 0.f, 0.f, 0.f);
          if (kg < K) v = *(const float4*)(Wrow + i * 4);
          unsigned short hx, lx, hy, ly, hz, lz, hw, lw;
          split_bf16(v.x, hx, lx);
          split_bf16(v.y, hy, ly);
          split_bf16(v.z, hz, lz);
          split_bf16(v.w, hw, lw);
          int idx = sr * 64 + ((sk + i * 4) ^ srx);
          *(ushort4*)&sWh[idx] = make_ushort4(hx, hy, hz, hw);
          *(ushort4*)&sWl[idx] = make_ushort4(lx, ly, lz, lw);
        }
      }
      __syncthreads();
      // ---- compute: 2 k-steps of 32 ----
#pragma unroll
      for (int ks = 0; ks < 2; ++ks) {
        bf16x8 ah[4], al[4];
#pragma unroll
        for (int i = 0; i < 4; ++i) {
          int r = wr * 64 + i * 16 + fr;
          int idx = r * 64 + ((ks * 32 + fk) ^ ((r & 7) << 3));
          ah[i] = *(const bf16x8*)&sAh[idx];
          al[i] = *(const bf16x8*)&sAl[idx];
        }
#pragma unroll
        for (int j = 0; j < 4; ++j) {
          int o = wc * 64 + j * 16 + fr;
          int idx = o * 64 + ((ks * 32 + fk) ^ ((o & 7) << 3));
          bf16x8 bh = *(const bf16x8*)&sWh[idx];
          bf16x8 bl = *(const bf16x8*)&sWl[idx];
#pragma unroll
          for (int i = 0; i < 4; ++i) {
            acc[i][j] = __builtin_amdgcn_mfma_f32_16x16x32_bf16(ah[i], bh, acc[i][j], 0, 0, 0);
            acc[i][j] = __builtin_amdgcn_mfma_f32_16x16x32_bf16(ah[i], bl, acc[i][j], 0, 0, 0);
            acc[i][j] = __builtin_amdgcn_mfma_f32_16x16x32_bf16(al[i], bh, acc[i][j], 0, 0, 0);
          }
        }
      }
      __syncthreads();
    }
  }

  // ---- epilogue: C/D layout col=lane&15, row=(lane>>4)*4+reg ----
  int crow0 = row0 + wr * 64 + (lane >> 4) * 4;
  int ccol0 = wc * 64 + (lane & 15);
#pragma unroll
  for (int j = 0; j < 4; ++j) {
    int col = ccol0 + j * 16;
    float b = bias[col];
#pragma unroll
    for (int i = 0; i < 4; ++i) {
#pragma unroll
      for (int rg = 0; rg < 4; ++rg) {
        int grow = crow0 + i * 16 + rg;
        if (grow < M) {
          float v = acc[i][j][rg] + b;
          if (RELU) v = fmaxf(v, 0.f);
          out[(size_t)grow * D_H + col] = v;
        }
      }
    }
  }
}

// ---------------- attention readout ----------------

__global__ __launch_bounds__(256) void k_score(const float* __restrict__ h,
                                               const float* __restrict__ watt,
                                               const float* __restrict__ batt,
                                               float* __restrict__ scores,
                                               float* __restrict__ partmax, int N) {
  __shared__ float smax[16];
  int t = threadIdx.x;
  int grp = t >> 4, l = t & 15;
  int node = blockIdx.x * 16 + grp;
  float sc = -3.0e38f;
  if (node < N) {
    const float2* hv = (const float2*)(h + (size_t)node * D_H);
    const float2* wv = (const float2*)watt;
    float acc = 0.f;
#pragma unroll
    for (int i = 0; i < 4; ++i) {
      float2 a = hv[i * 16 + l];
      float2 w = wv[i * 16 + l];
      acc = fmaf(a.x, w.x, acc);
      acc = fmaf(a.y, w.y, acc);
    }
#pragma unroll
    for (int off = 8; off > 0; off >>= 1) acc += __shfl_down(acc, off, 16);
    if (l == 0) {
      sc = acc + batt[0];
      scores[node] = sc;
    }
  }
  if (l == 0) smax[grp] = sc;
  __syncthreads();
  if (t == 0) {
    float m = smax[0];
    for (int i = 1; i < 16; ++i) m = fmaxf(m, smax[i]);
    partmax[blockIdx.x] = m;
  }
}

__global__ __launch_bounds__(256) void k_redmax(const float* __restrict__ partmax, int PB,
                                                float* __restrict__ red) {
  __shared__ float sm[256];
  int t = threadIdx.x;
  float m = -3.0e38f;
  for (int i = t; i < PB; i += 256) m = fmaxf(m, partmax[i]);
  sm[t] = m;
  __syncthreads();
  for (int off = 128; off > 0; off >>= 1) {
    if (t < off) sm[t] = fmaxf(sm[t], sm[t + off]);
    __syncthreads();
  }
  if (t == 0) {
    red[0] = sm[0];
    red[1] = 0.f;
  }
  for (int i = t; i < 1024; i += 256) red[2 + i] = 0.f;
}

__global__ __launch_bounds__(256) void k_pool(const float* __restrict__ h,
                                              const float* __restrict__ scores,
                                              const int* __restrict__ batch,
                                              float* __restrict__ red, int N, int nblocks) {
  __shared__ float pl[4][1024];
  __shared__ float zp[4];
  int t = threadIdx.x;
  int w = t >> 6, lane = t & 63;
  for (int i = lane; i < 1024; i += 64) pl[w][i] = 0.f;
  float M = red[0];
  float zacc = 0.f;
  const float2* hv = (const float2*)h;
  int stride = nblocks * 4;
  for (int node = blockIdx.x * 4 + w; node < N; node += stride) {
    float wgt = __expf(scores[node] - M);
    int b = batch[node];
    float2 v = hv[(size_t)node * 64 + lane];
    pl[w][b * 128 + lane * 2] += v.x * wgt;
    pl[w][b * 128 + lane * 2 + 1] += v.y * wgt;
    zacc += wgt;
  }
  if (lane == 0) zp[w] = zacc;
  __syncthreads();
  for (int i = t; i < 1024; i += 256) {
    float s = pl[0][i] + pl[1][i] + pl[2][i] + pl[3][i];
    atomicAdd(&red[2 + i], s);
  }
  if (t == 0) atomicAdd(&red[1], zp[0] + zp[1] + zp[2] + zp[3]);
}

__global__ __launch_bounds__(512) void k_out(const float* __restrict__ red,
                                             const float* __restrict__ Wout,
                                             const float* __restrict__ bout,
                                             float* __restrict__ out) {
  int t = threadIdx.x;
  int gIdx = t >> 6, o = t & 63;
  float invZ = 1.f / red[1];
  const float* p = red + 2 + gIdx * 128;
  const float* wr = Wout + (size_t)o * 128;
  float acc = 0.f;
  for (int k = 0; k < 128; ++k) acc = fmaf(p[k], wr[k], acc);
  out[gIdx * 64 + o] = acc * invZ + bout[o];
}

// ---------------- launcher ----------------

extern "C" void kernel_launch(void* const* d_in, const int* in_sizes, int n_in,
                              void* d_out, int out_size, void* d_ws, size_t ws_size,
                              hipStream_t stream) {
  const float* x     = (const float*)d_in[0];
  const int*   ei    = (const int*)d_in[1];
  const int*   batch = (const int*)d_in[2];
  const float* W_emb = (const float*)d_in[3];
  const float* b_emb = (const float*)d_in[4];
  const float* Wl0   = (const float*)d_in[5];
  const float* bl0   = (const float*)d_in[6];
  const float* Wr0   = (const float*)d_in[7];
  const float* Wl1   = (const float*)d_in[8];
  const float* bl1   = (const float*)d_in[9];
  const float* Wr1   = (const float*)d_in[10];
  const float* W_att = (const float*)d_in[11];
  const float* b_att = (const float*)d_in[12];
  const float* W_out = (const float*)d_in[13];
  const float* b_out = (const float*)d_in[14];
  float* out = (float*)d_out;

  const int DIN = 300;
  int N = in_sizes[0] / DIN;
  int E = in_sizes[1] / 2;

  char* wsp = (char*)d_ws;
  size_t off = 0;
  auto carve = [&](size_t bytes) -> void* {
    void* p = wsp + off;
    off += (bytes + 255) & ~(size_t)255;
    return p;
  };
  float* A       = (float*)carve((size_t)N * D_H * 4);
  float* B       = (float*)carve((size_t)N * D_H * 4);
  int*   colA    = (int*)carve((size_t)E * 4);
  int*   row_ptr = (int*)carve((size_t)(N + 1) * 4);
  int*   deg     = (int*)carve((size_t)N * 4);
  int*   cnt     = (int*)carve((size_t)N * 4);
  float* scores  = (float*)carve((size_t)N * 4);
  int scoreBlocks = (N + 15) / 16;
  float* partmax = (float*)carve((size_t)scoreBlocks * 4);
  float* red     = (float*)carve((size_t)(2 + 1024) * 4);
  int scanBlocks = (N + 255) / 256;
  int*   partials = (int*)carve((size_t)scanBlocks * 4);

  const int* srcv = ei;
  const int* dstv = ei + E;

  hipMemsetAsync(deg, 0, (size_t)N * 4, stream);
  k_deg<<<1024, 256, 0, stream>>>(dstv, deg, E);
  k_partial<<<scanBlocks, 256, 0, stream>>>(deg, partials, N);
  k_scanpart<<<1, 256, 0, stream>>>(partials, scanBlocks, row_ptr, N);
  k_rowptr<<<scanBlocks, 256, 0, stream>>>(deg, partials, row_ptr, cnt, N);
  k_scatter<<<1024, 256, 0, stream>>>(srcv, dstv, cnt, colA, E);

  int gblocks = (N + 127) / 128;
  k_gemm<false, false><<<gblocks, 256, 0, stream>>>(x, W_emb, DIN, nullptr, nullptr, 0,
                                                    b_emb, A, N);
  k_aggregate<<<(N + 3) / 4, 256, 0, stream>>>(A, row_ptr, colA, B, N);
  k_gemm<true, true><<<gblocks, 256, 0, stream>>>(B, Wl0, D_H, A, Wr0, D_H, bl0, B, N);
  k_aggregate<<<(N + 3) / 4, 256, 0, stream>>>(B, row_ptr, colA, A, N);
  k_gemm<true, true><<<gblocks, 256, 0, stream>>>(A, Wl1, D_H, B, Wr1, D_H, bl1, A, N);

  k_score<<<scoreBlocks, 256, 0, stream>>>(A, W_att, b_att, scores, partmax, N);
  k_redmax<<<1, 256, 0, stream>>>(partmax, scoreBlocks, red);
  k_pool<<<256, 256, 0, stream>>>(A, scores, batch, red, N, 256);
  k_out<<<1, 512, 0, stream>>>(red, W_out, b_out, out);
}

// Round 4
// 352.566 us; speedup vs baseline: 1.5033x; 1.0715x over previous
//
#include <hip/hip_runtime.h>
#include <math.h>

#define D_H 128

typedef __attribute__((ext_vector_type(8))) __bf16 bf16x8;
typedef __attribute__((ext_vector_type(4))) float f32x4;

__device__ __forceinline__ void split_bf16(float v, unsigned short& hi, unsigned short& lo) {
  unsigned int u = __float_as_uint(v);
  hi = (unsigned short)(u >> 16);
  float l = v - __uint_as_float(u & 0xffff0000u);
  lo = (unsigned short)(__float_as_uint(l) >> 16);
}

__device__ __forceinline__ float blo(unsigned int u) { return __uint_as_float(u << 16); }
__device__ __forceinline__ float bhi(unsigned int u) { return __uint_as_float(u & 0xffff0000u); }

__device__ __forceinline__ void load_lds16(const void* g, void* l) {
  __builtin_amdgcn_global_load_lds((const __attribute__((address_space(1))) unsigned int*)g,
                                   (__attribute__((address_space(3))) unsigned int*)l,
                                   16, 0, 0);
}

// ---------------- graph build ----------------

__global__ void k_deg(const int* __restrict__ dstv, int* __restrict__ deg, int E) {
  for (int i = blockIdx.x * blockDim.x + threadIdx.x; i < E; i += gridDim.x * blockDim.x)
    atomicAdd(&deg[dstv[i]], 1);
}

__global__ __launch_bounds__(256) void k_partial(const int* __restrict__ deg,
                                                 int* __restrict__ partials, int N) {
  __shared__ int s[256];
  int t = threadIdx.x;
  int i = blockIdx.x * 256 + t;
  s[t] = (i < N) ? deg[i] : 0;
  __syncthreads();
  for (int off = 128; off > 0; off >>= 1) {
    if (t < off) s[t] += s[t + off];
    __syncthreads();
  }
  if (t == 0) partials[blockIdx.x] = s[0];
}

__global__ __launch_bounds__(256) void k_scanpart(int* __restrict__ partials, int NB,
                                                  int* __restrict__ row_ptr, int N) {
  __shared__ int s[256];
  int t = threadIdx.x;
  int v = (t < NB) ? partials[t] : 0;
  s[t] = v;
  __syncthreads();
  for (int off = 1; off < 256; off <<= 1) {
    int u = (t >= off) ? s[t - off] : 0;
    __syncthreads();
    s[t] += u;
    __syncthreads();
  }
  if (t < NB) partials[t] = s[t] - v;
  if (t == 255) row_ptr[N] = s[255];
}

__global__ __launch_bounds__(256) void k_rowptr(const int* __restrict__ deg,
                                                const int* __restrict__ partials,
                                                int* __restrict__ row_ptr,
                                                int* __restrict__ cnt, int N) {
  __shared__ int s[256];
  int t = threadIdx.x;
  int i = blockIdx.x * 256 + t;
  int v = (i < N) ? deg[i] : 0;
  s[t] = v;
  __syncthreads();
  for (int off = 1; off < 256; off <<= 1) {
    int u = (t >= off) ? s[t - off] : 0;
    __syncthreads();
    s[t] += u;
    __syncthreads();
  }
  if (i < N) {
    int ex = partials[blockIdx.x] + s[t] - v;
    row_ptr[i] = ex;
    cnt[i] = ex;
  }
}

__global__ void k_scatter(const int* __restrict__ srcv, const int* __restrict__ dstv,
                          int* __restrict__ cnt, int* __restrict__ col, int E) {
  for (int i = blockIdx.x * blockDim.x + threadIdx.x; i < E; i += gridDim.x * blockDim.x) {
    int d = dstv[i];
    int pos = atomicAdd(&cnt[d], 1);
    col[pos] = srcv[i];
  }
}

// ---------------- weight split (once) ----------------
// pair layout: row = [K hi shorts | K lo shorts]; emb K padded 300->320 (zeros)

__global__ __launch_bounds__(256) void k_wsplit(
    const float* __restrict__ Wemb, const float* __restrict__ Wl0,
    const float* __restrict__ Wr0, const float* __restrict__ Wl1,
    const float* __restrict__ Wr1, unsigned short* __restrict__ WembP,
    unsigned short* __restrict__ P0l, unsigned short* __restrict__ P0r,
    unsigned short* __restrict__ P1l, unsigned short* __restrict__ P1r) {
  int tid = blockIdx.x * 256 + threadIdx.x;
  const int EMB = 128 * 320;
  if (tid < EMB) {
    int o = tid / 320, k = tid - o * 320;
    float v = (k < 300) ? Wemb[o * 300 + k] : 0.f;
    unsigned short h, l;
    split_bf16(v, h, l);
    WembP[o * 640 + k] = h;
    WembP[o * 640 + 320 + k] = l;
  } else if (tid < EMB + 4 * 16384) {
    int r = tid - EMB;
    int m = r >> 14;
    int i = r & 16383;
    int o = i >> 7, k = i & 127;
    const float* W = (m == 0) ? Wl0 : (m == 1) ? Wr0 : (m == 2) ? Wl1 : Wr1;
    unsigned short* P = (m == 0) ? P0l : (m == 1) ? P0r : (m == 2) ? P1l : P1r;
    unsigned short h, l;
    split_bf16(W[o * 128 + k], h, l);
    P[o * 256 + k] = h;
    P[o * 256 + 128 + k] = l;
  }
}

// ---------------- mean aggregation on pair format ----------------
// in/out rows: [128 hi | 128 lo] shorts (512 B). One wave per node; lanes 0-31
// accumulate hi-part of dims (lane&31)*4..+3, lanes 32-63 the lo-part; shfl_xor
// combines, then each half writes its half of the output pair.

__global__ __launch_bounds__(256) void k_aggregate(const unsigned short* __restrict__ hp,
                                                   const int* __restrict__ row_ptr,
                                                   const int* __restrict__ col,
                                                   unsigned short* __restrict__ outp, int N) {
  int wid = blockIdx.x * 4 + (threadIdx.x >> 6);
  if (wid >= N) return;
  int lane = threadIdx.x & 63;
  int half = lane >> 5;
  int dl = (lane & 31) * 4;
  int off = half * 128 + dl;
  int e0 = row_ptr[wid], e1 = row_ptr[wid + 1];
  float a0 = 0.f, a1 = 0.f, a2 = 0.f, a3 = 0.f;
  int e = e0;
  for (; e + 4 <= e1; e += 4) {
    int s0 = col[e], s1 = col[e + 1], s2 = col[e + 2], s3 = col[e + 3];
    uint2 u0 = *(const uint2*)(hp + (size_t)s0 * 256 + off);
    uint2 u1 = *(const uint2*)(hp + (size_t)s1 * 256 + off);
    uint2 u2 = *(const uint2*)(hp + (size_t)s2 * 256 + off);
    uint2 u3 = *(const uint2*)(hp + (size_t)s3 * 256 + off);
    a0 += blo(u0.x) + blo(u1.x) + blo(u2.x) + blo(u3.x);
    a1 += bhi(u0.x) + bhi(u1.x) + bhi(u2.x) + bhi(u3.x);
    a2 += blo(u0.y) + blo(u1.y) + blo(u2.y) + blo(u3.y);
    a3 += bhi(u0.y) + bhi(u1.y) + bhi(u2.y) + bhi(u3.y);
  }
  for (; e < e1; ++e) {
    uint2 u = *(const uint2*)(hp + (size_t)col[e] * 256 + off);
    a0 += blo(u.x);
    a1 += bhi(u.x);
    a2 += blo(u.y);
    a3 += bhi(u.y);
  }
  a0 += __shfl_xor(a0, 32);
  a1 += __shfl_xor(a1, 32);
  a2 += __shfl_xor(a2, 32);
  a3 += __shfl_xor(a3, 32);
  float inv = 1.f / fmaxf((float)(e1 - e0), 1.f);
  a0 *= inv;
  a1 *= inv;
  a2 *= inv;
  a3 *= inv;
  unsigned short h0, l0, h1, l1, h2, l2, h3, l3;
  split_bf16(a0, h0, l0);
  split_bf16(a1, h1, l1);
  split_bf16(a2, h2, l2);
  split_bf16(a3, h3, l3);
  if (half == 0)
    *(ushort4*)&outp[(size_t)wid * 256 + dl] = make_ushort4(h0, h1, h2, h3);
  else
    *(ushort4*)&outp[(size_t)wid * 256 + 128 + dl] = make_ushort4(l0, l1, l2, l3);
}

// ---------------- split-bf16 MFMA GEMM, gload_lds staging ----------------
// Block 128 rows x 128 cols, 4 waves 2x2 (64x64 wave tiles), BK=32.
// LDS tile row = 144 B: [32 hi shorts | 32 lo shorts | 8 pad shorts].
// 144 B = 36 banks -> 4-bank shift per row -> 2-way (free) on ds_read_b128.
// Staged with global_load_lds (linear LDS dest); per-lane SOURCE address does
// the row/col remap, reading from pair rows [K hi | K lo].

template <int AMODE /*0=fp32 A, in-kernel split; 1=pair A via gload_lds*/,
          int KPAD, bool DUAL, bool RELU, int OMODE /*0=f32 out, 1=pair out*/>
__global__ __launch_bounds__(256, 3) void k_gemm(
    const float* __restrict__ A1f, const char* __restrict__ A1p,
    const char* __restrict__ W1p, int K1, const char* __restrict__ A2p,
    const char* __restrict__ W2p, const float* __restrict__ bias,
    float* __restrict__ outf, unsigned short* __restrict__ outp, int M) {
  __shared__ alignas(16) short sA[128 * 72];
  __shared__ alignas(16) short sW[128 * 72];

  int t = threadIdx.x;
  int lane = t & 63;
  int wave = t >> 6;
  int wr = wave >> 1, wc = wave & 1;
  int row0 = blockIdx.x * 128;
  int lane16 = lane * 16;

  f32x4 acc[4][4] = {};
  int fr = lane & 15;
  int fk = (lane >> 4) * 8;

  const int NT1 = KPAD / 32;
  const int NTtot = NT1 + (DUAL ? 4 : 0);

  for (int tt = 0; tt < NTtot; ++tt) {
    bool p2 = DUAL && (tt >= NT1);
    int ks = p2 ? tt - NT1 : tt;
    int kb = ks * 64;  // byte offset of k-slice in hi region

    // ---- stage W pair -> sW (18 chunks of 1024 B) ----
    {
      const char* Wp = p2 ? W2p : W1p;
      int wrb = p2 ? 512 : (KPAD * 4);
      int wlo = wrb >> 1;
      for (int c = wave; c < 18; c += 4) {
        int o = c * 1024 + lane16;
        int row = o / 144;
        int win = o - row * 144;
        int w2 = (win >= 128) ? win - 128 : win;
        int so = (w2 < 64) ? (kb + w2) : (wlo + kb + (w2 - 64));
        load_lds16(Wp + row * wrb + so, (char*)sW + c * 1024);
      }
    }
    // ---- stage A ----
    if (AMODE == 1) {
      const char* Ap = p2 ? A2p : A1p;
      for (int c = wave; c < 18; c += 4) {
        int o = c * 1024 + lane16;
        int row = o / 144;
        int win = o - row * 144;
        int w2 = (win >= 128) ? win - 128 : win;
        int so = (w2 < 64) ? (kb + w2) : (256 + kb + (w2 - 64));
        load_lds16(Ap + (size_t)(row0 + row) * 512 + so, (char*)sA + c * 1024);
      }
    } else {
      int sr = t >> 1;
      int kh = (t & 1) * 16;
      int grow = row0 + sr;
      bool rok = grow < M;
      const float* Arow = A1f + (size_t)grow * K1 + ks * 32 + kh;
#pragma unroll
      for (int i = 0; i < 4; ++i) {
        int kg = ks * 32 + kh + i * 4;
        float4 v = make_float4(0.f, 0.f, 0.f, 0.f);
        if (rok && kg + 3 < K1) v = *(const float4*)(Arow + i * 4);
        unsigned short hx, lx, hy, ly, hz, lz, hw, lw;
        split_bf16(v.x, hx, lx);
        split_bf16(v.y, hy, ly);
        split_bf16(v.z, hz, lz);
        split_bf16(v.w, hw, lw);
        int base = sr * 72 + kh + i * 4;
        *(ushort4*)&sA[base] = make_ushort4(hx, hy, hz, hw);
        *(ushort4*)&sA[base + 32] = make_ushort4(lx, ly, lz, lw);
      }
    }
    __syncthreads();

    // ---- compute one 32-k step ----
    bf16x8 ah[4], al[4];
#pragma unroll
    for (int i = 0; i < 4; ++i) {
      int r = wr * 64 + i * 16 + fr;
      ah[i] = *(const bf16x8*)&sA[r * 72 + fk];
      al[i] = *(const bf16x8*)&sA[r * 72 + 32 + fk];
    }
#pragma unroll
    for (int j = 0; j < 4; ++j) {
      int o = wc * 64 + j * 16 + fr;
      bf16x8 bh = *(const bf16x8*)&sW[o * 72 + fk];
      bf16x8 bl = *(const bf16x8*)&sW[o * 72 + 32 + fk];
#pragma unroll
      for (int i = 0; i < 4; ++i) {
        acc[i][j] = __builtin_amdgcn_mfma_f32_16x16x32_bf16(ah[i], bh, acc[i][j], 0, 0, 0);
        acc[i][j] = __builtin_amdgcn_mfma_f32_16x16x32_bf16(ah[i], bl, acc[i][j], 0, 0, 0);
        acc[i][j] = __builtin_amdgcn_mfma_f32_16x16x32_bf16(al[i], bh, acc[i][j], 0, 0, 0);
      }
    }
    __syncthreads();
  }

  // ---- epilogue: C/D layout col=lane&15, row=(lane>>4)*4+reg ----
  int crow0 = row0 + wr * 64 + (lane >> 4) * 4;
  int ccol0 = wc * 64 + (lane & 15);
#pragma unroll
  for (int j = 0; j < 4; ++j) {
    int col = ccol0 + j * 16;
    float b = bias[col];
#pragma unroll
    for (int i = 0; i < 4; ++i) {
#pragma unroll
      for (int rg = 0; rg < 4; ++rg) {
        int grow = crow0 + i * 16 + rg;
        if (grow < M) {
          float v = acc[i][j][rg] + b;
          if (RELU) v = fmaxf(v, 0.f);
          if (OMODE == 0) {
            outf[(size_t)grow * D_H + col] = v;
          } else {
            unsigned short h, l;
            split_bf16(v, h, l);
            outp[(size_t)grow * 256 + col] = h;
            outp[(size_t)grow * 256 + 128 + col] = l;
          }
        }
      }
    }
  }
}

// ---------------- attention readout (fp32 h) ----------------

__global__ __launch_bounds__(256) void k_score(const float* __restrict__ h,
                                               const float* __restrict__ watt,
                                               const float* __restrict__ batt,
                                               float* __restrict__ scores,
                                               float* __restrict__ partmax, int N) {
  __shared__ float smax[16];
  int t = threadIdx.x;
  int grp = t >> 4, l = t & 15;
  int node = blockIdx.x * 16 + grp;
  float sc = -3.0e38f;
  if (node < N) {
    const float2* hv = (const float2*)(h + (size_t)node * D_H);
    const float2* wv = (const float2*)watt;
    float acc = 0.f;
#pragma unroll
    for (int i = 0; i < 4; ++i) {
      float2 a = hv[i * 16 + l];
      float2 w = wv[i * 16 + l];
      acc = fmaf(a.x, w.x, acc);
      acc = fmaf(a.y, w.y, acc);
    }
#pragma unroll
    for (int off = 8; off > 0; off >>= 1) acc += __shfl_down(acc, off, 16);
    if (l == 0) {
      sc = acc + batt[0];
      scores[node] = sc;
    }
  }
  if (l == 0) smax[grp] = sc;
  __syncthreads();
  if (t == 0) {
    float m = smax[0];
    for (int i = 1; i < 16; ++i) m = fmaxf(m, smax[i]);
    partmax[blockIdx.x] = m;
  }
}

__global__ __launch_bounds__(256) void k_redmax(const float* __restrict__ partmax, int PB,
                                                float* __restrict__ red) {
  __shared__ float sm[256];
  int t = threadIdx.x;
  float m = -3.0e38f;
  for (int i = t; i < PB; i += 256) m = fmaxf(m, partmax[i]);
  sm[t] = m;
  __syncthreads();
  for (int off = 128; off > 0; off >>= 1) {
    if (t < off) sm[t] = fmaxf(sm[t], sm[t + off]);
    __syncthreads();
  }
  if (t == 0) {
    red[0] = sm[0];
    red[1] = 0.f;
  }
  for (int i = t; i < 1024; i += 256) red[2 + i] = 0.f;
}

__global__ __launch_bounds__(256) void k_pool(const float* __restrict__ h,
                                              const float* __restrict__ scores,
                                              const int* __restrict__ batch,
                                              float* __restrict__ red, int N, int nblocks) {
  __shared__ float pl[4][1024];
  __shared__ float zp[4];
  int t = threadIdx.x;
  int w = t >> 6, lane = t & 63;
  for (int i = lane; i < 1024; i += 64) pl[w][i] = 0.f;
  float M = red[0];
  float zacc = 0.f;
  const float2* hv = (const float2*)h;
  int stride = nblocks * 4;
  for (int node = blockIdx.x * 4 + w; node < N; node += stride) {
    float wgt = __expf(scores[node] - M);
    int b = batch[node];
    float2 v = hv[(size_t)node * 64 + lane];
    pl[w][b * 128 + lane * 2] += v.x * wgt;
    pl[w][b * 128 + lane * 2 + 1] += v.y * wgt;
    zacc += wgt;
  }
  if (lane == 0) zp[w] = zacc;
  __syncthreads();
  for (int i = t; i < 1024; i += 256) {
    float s = pl[0][i] + pl[1][i] + pl[2][i] + pl[3][i];
    atomicAdd(&red[2 + i], s);
  }
  if (t == 0) atomicAdd(&red[1], zp[0] + zp[1] + zp[2] + zp[3]);
}

__global__ __launch_bounds__(512) void k_out(const float* __restrict__ red,
                                             const float* __restrict__ Wout,
                                             const float* __restrict__ bout,
                                             float* __restrict__ out) {
  int t = threadIdx.x;
  int gIdx = t >> 6, o = t & 63;
  float invZ = 1.f / red[1];
  const float* p = red + 2 + gIdx * 128;
  const float* wr = Wout + (size_t)o * 128;
  float acc = 0.f;
  for (int k = 0; k < 128; ++k) acc = fmaf(p[k], wr[k], acc);
  out[gIdx * 64 + o] = acc * invZ + bout[o];
}

// ---------------- launcher ----------------

extern "C" void kernel_launch(void* const* d_in, const int* in_sizes, int n_in,
                              void* d_out, int out_size, void* d_ws, size_t ws_size,
                              hipStream_t stream) {
  const float* x     = (const float*)d_in[0];
  const int*   ei    = (const int*)d_in[1];
  const int*   batch = (const int*)d_in[2];
  const float* W_emb = (const float*)d_in[3];
  const float* b_emb = (const float*)d_in[4];
  const float* Wl0   = (const float*)d_in[5];
  const float* bl0   = (const float*)d_in[6];
  const float* Wr0   = (const float*)d_in[7];
  const float* Wl1   = (const float*)d_in[8];
  const float* bl1   = (const float*)d_in[9];
  const float* Wr1   = (const float*)d_in[10];
  const float* W_att = (const float*)d_in[11];
  const float* b_att = (const float*)d_in[12];
  const float* W_out = (const float*)d_in[13];
  const float* b_out = (const float*)d_in[14];
  float* out = (float*)d_out;

  const int DIN = 300;
  int N = in_sizes[0] / DIN;
  int E = in_sizes[1] / 2;
  int Npad = (N + 127) & ~127;

  char* wsp = (char*)d_ws;
  size_t off = 0;
  auto carve = [&](size_t bytes) -> void* {
    void* p = wsp + off;
    off += (bytes + 255) & ~(size_t)255;
    return p;
  };
  unsigned short* P  = (unsigned short*)carve((size_t)Npad * 512);  // h pairs
  unsigned short* Gp = (unsigned short*)carve((size_t)Npad * 512);  // agg pairs / final f32 h
  unsigned short* WembP = (unsigned short*)carve((size_t)128 * 640 * 2);
  unsigned short* WP0l  = (unsigned short*)carve((size_t)128 * 256 * 2);
  unsigned short* WP0r  = (unsigned short*)carve((size_t)128 * 256 * 2);
  unsigned short* WP1l  = (unsigned short*)carve((size_t)128 * 256 * 2);
  unsigned short* WP1r  = (unsigned short*)carve((size_t)128 * 256 * 2);
  int*   colA    = (int*)carve((size_t)E * 4);
  int*   row_ptr = (int*)carve((size_t)(N + 1) * 4);
  int*   deg     = (int*)carve((size_t)N * 4);
  int*   cnt     = (int*)carve((size_t)N * 4);
  float* scores  = (float*)carve((size_t)N * 4);
  int scoreBlocks = (N + 15) / 16;
  float* partmax = (float*)carve((size_t)scoreBlocks * 4);
  float* red     = (float*)carve((size_t)(2 + 1024) * 4);
  int scanBlocks = (N + 255) / 256;
  int*   partials = (int*)carve((size_t)scanBlocks * 4);

  const int* srcv = ei;
  const int* dstv = ei + E;

  hipMemsetAsync(deg, 0, (size_t)N * 4, stream);
  k_deg<<<1024, 256, 0, stream>>>(dstv, deg, E);
  k_wsplit<<<(128 * 320 + 4 * 16384 + 255) / 256, 256, 0, stream>>>(
      W_emb, Wl0, Wr0, Wl1, Wr1, WembP, WP0l, WP0r, WP1l, WP1r);
  k_partial<<<scanBlocks, 256, 0, stream>>>(deg, partials, N);
  k_scanpart<<<1, 256, 0, stream>>>(partials, scanBlocks, row_ptr, N);
  k_rowptr<<<scanBlocks, 256, 0, stream>>>(deg, partials, row_ptr, cnt, N);
  k_scatter<<<1024, 256, 0, stream>>>(srcv, dstv, cnt, colA, E);

  int gblocks = Npad / 128;
  // emb: h0 = x @ Wemb^T + b  (pair out)
  k_gemm<0, 320, false, false, 1><<<gblocks, 256, 0, stream>>>(
      x, nullptr, (const char*)WembP, DIN, nullptr, nullptr, b_emb, nullptr, P, N);
  // agg0: Gp = mean-agg(P)
  k_aggregate<<<(N + 3) / 4, 256, 0, stream>>>(P, row_ptr, colA, Gp, N);
  // conv0: h1 = relu(Gp@Wl0^T + bl0 + P@Wr0^T)  (pair out, in-place over P)
  k_gemm<1, 128, true, true, 1><<<gblocks, 256, 0, stream>>>(
      nullptr, (const char*)Gp, (const char*)WP0l, 128, (const char*)P,
      (const char*)WP0r, bl0, nullptr, P, N);
  // agg1
  k_aggregate<<<(N + 3) / 4, 256, 0, stream>>>(P, row_ptr, colA, Gp, N);
  // conv1: h2 = relu(...)  (f32 out, in-place over Gp)
  k_gemm<1, 128, true, true, 0><<<gblocks, 256, 0, stream>>>(
      nullptr, (const char*)Gp, (const char*)WP1l, 128, (const char*)P,
      (const char*)WP1r, bl1, (float*)Gp, nullptr, N);

  const float* h2 = (const float*)Gp;
  k_score<<<scoreBlocks, 256, 0, stream>>>(h2, W_att, b_att, scores, partmax, N);
  k_redmax<<<1, 256, 0, stream>>>(partmax, scoreBlocks, red);
  k_pool<<<256, 256, 0, stream>>>(h2, scores, batch, red, N, 256);
  k_out<<<1, 512, 0, stream>>>(red, W_out, b_out, out);
}